// Round 3
// baseline (3472.225 us; speedup 1.0000x reference)
//
#include <hip/hip_runtime.h>

typedef unsigned short u16;
typedef __bf16 bf16x8 __attribute__((ext_vector_type(8)));
typedef float f32x4 __attribute__((ext_vector_type(4)));
typedef unsigned short u16x4 __attribute__((ext_vector_type(4)));
typedef unsigned short u16x8 __attribute__((ext_vector_type(8)));

__device__ __forceinline__ u16 f2bf(float f) {
    union { float f; unsigned u; } v; v.f = f;
    unsigned r = v.u + 0x7FFFu + ((v.u >> 16) & 1u);   // RTNE
    return (u16)(r >> 16);
}
__device__ __forceinline__ float bf2f(u16 h) {
    union { unsigned u; float f; } v; v.u = ((unsigned)h) << 16;
    return v.f;
}

// async global->LDS, 16B per lane; LDS dest is wave-uniform base + lane*16
__device__ __forceinline__ void gl_lds16(const void* gp, void* lp) {
    __builtin_amdgcn_global_load_lds(
        reinterpret_cast<__attribute__((address_space(1))) unsigned int*>(
            reinterpret_cast<size_t>(gp)),
        reinterpret_cast<__attribute__((address_space(3))) unsigned int*>(
            reinterpret_cast<size_t>(lp)),
        16, 0, 0);
}

// GROUP_M=8 swizzle for the 128-tile fallback kernel
__device__ __forceinline__ void swz(int bid, int nb, int& mb, int& nbk) {
    int gs  = nb << 3;
    int grp = bid / gs;
    int rem = bid - grp * gs;
    mb  = (grp << 3) + (rem & 7);
    nbk = rem >> 3;
}

// ---- x fp32 -> bf16, 8 elems/thread, exact grid ----
__global__ __launch_bounds__(256) void xcvt(const float* __restrict__ x,
                                            u16* __restrict__ xb) {
    size_t i = ((size_t)blockIdx.x * 256 + threadIdx.x) * 8;
    float4 a = *(const float4*)(x + i);
    float4 b = *(const float4*)(x + i + 4);
    u16x8 p;
    p[0] = f2bf(a.x); p[1] = f2bf(a.y); p[2] = f2bf(a.z); p[3] = f2bf(a.w);
    p[4] = f2bf(b.x); p[5] = f2bf(b.y); p[6] = f2bf(b.z); p[7] = f2bf(b.w);
    *(u16x8*)(xb + i) = p;
}

// ---- transpose-dequant via LDS: q[K,N] int32 -> wt[N,K] bf16 ----
__global__ __launch_bounds__(256) void dequant_t(
    const int* __restrict__ q, const float* __restrict__ s,
    const float* __restrict__ z, u16* __restrict__ wt, int K, int N)
{
    __shared__ u16 ls[64 * 132];
    const int n0 = blockIdx.x * 64, k0 = blockIdx.y * 128;
    const int g  = k0 >> 7;
    const int t  = threadIdx.x;
    const int n4 = (t & 15) * 4;
    const int kb = t >> 4;
    float sv[4], zv[4];
#pragma unroll
    for (int j = 0; j < 4; ++j) {
        sv[j] = s[(size_t)g * N + n0 + n4 + j];
        zv[j] = z[(size_t)g * N + n0 + n4 + j];
    }
#pragma unroll
    for (int p = 0; p < 8; ++p) {
        int kk = kb + p * 16;
        int4 qv = *(const int4*)(q + (size_t)(k0 + kk) * N + n0 + n4);
        ls[(n4 + 0) * 132 + kk] = f2bf((float)(qv.x - 8) * sv[0] + zv[0]);
        ls[(n4 + 1) * 132 + kk] = f2bf((float)(qv.y - 8) * sv[1] + zv[1]);
        ls[(n4 + 2) * 132 + kk] = f2bf((float)(qv.z - 8) * sv[2] + zv[2]);
        ls[(n4 + 3) * 132 + kk] = f2bf((float)(qv.w - 8) * sv[3] + zv[3]);
    }
    __syncthreads();
    const int r = t >> 2, c = t & 3;
    const u16* src = &ls[r * 132 + c * 32];
    u16* dst = &wt[(size_t)(n0 + r) * K + k0 + c * 32];
#pragma unroll
    for (int i = 0; i < 4; ++i) {
        u16x4 a = *(const u16x4*)(src + i * 8);
        u16x4 b = *(const u16x4*)(src + i * 8 + 4);
        u16x8 v;
        v[0] = a[0]; v[1] = a[1]; v[2] = a[2]; v[3] = a[3];
        v[4] = b[0]; v[5] = b[1]; v[6] = b[2]; v[7] = b[3];
        *(u16x8*)(dst + i * 8) = v;
    }
}

// ---- 128(M)x256(N)-tile GEMM, 256 threads = 4 waves (1M x 4N), BK=32.
// 3-buffer pipeline (72 KiB LDS -> 2 blocks/CU: two independent barrier
// domains per CU so one block's MFMA covers the other's sync/LDS stalls).
// Tile t+2 staged (global_load_lds, linear dest + inverse-swizzled source)
// while tile t computes; ONE barrier per K-step; counted vmcnt(6) per step
// (6 loads/tile/thread: 2 A + 4 B), drains to 0 only at the last prefetch.
// Swizzle: chunk slot h = kc ^ ((row>>1)&3) -> conflict-free ds_read_b128.
// EPI: 0 = store bf16 to gh; 1 = gh = silu(gh)*acc (in place); 2 = fp32 out.
template <int EPI>
__global__ __launch_bounds__(256, 2) void gemmC(
    const u16* __restrict__ A, const u16* __restrict__ Bt,
    u16* __restrict__ gh, float* __restrict__ outp, int M, int N, int K)
{
    __shared__ __align__(16) u16 A_s[3][128 * 32];   //  8 KB / buf
    __shared__ __align__(16) u16 B_s[3][256 * 32];   // 16 KB / buf

    const int nb  = N >> 8;
    const int bid = blockIdx.x;
    const int nwg = gridDim.x;           // % 8 == 0 by launch
    const int cpx = nwg >> 3;            // XCD-bijective swizzle
    const int wg  = (bid & 7) * cpx + (bid >> 3);
    const int mb  = wg / nb;
    const int nbk = wg - mb * nb;
    const int m0 = mb << 7, n0 = nbk << 8;

    const int t = threadIdx.x, lane = t & 63, w = t >> 6;   // w = n-quadrant
    const int lr = lane & 15;
    const int hofs = (((lane >> 4) ^ ((lane >> 1) & 3)) << 3);

    f32x4 acc[8][4] = {};
    const int NT = K >> 5;

#define STAGE_A(TT, SB)                                                     \
    {                                                                       \
        const int ko_ = (TT) * 32;                                          \
        _Pragma("unroll")                                                   \
        for (int l_ = 0; l_ < 2; ++l_) {                                    \
            int f_ = l_ * 256 + t;                                          \
            int r_ = f_ >> 2;                                               \
            int kc_ = (f_ & 3) ^ ((r_ >> 1) & 3);                           \
            gl_lds16(A + (size_t)(m0 + r_) * K + ko_ + kc_ * 8,             \
                     (char*)&A_s[SB][0] + (size_t)f_ * 16);                 \
        }                                                                   \
    }
#define STAGE_B(TT, SB)                                                     \
    {                                                                       \
        const int ko_ = (TT) * 32;                                          \
        _Pragma("unroll")                                                   \
        for (int l_ = 0; l_ < 4; ++l_) {                                    \
            int f_ = l_ * 256 + t;                                          \
            int r_ = f_ >> 2;                                               \
            int kc_ = (f_ & 3) ^ ((r_ >> 1) & 3);                           \
            gl_lds16(Bt + (size_t)(n0 + r_) * K + ko_ + kc_ * 8,            \
                     (char*)&B_s[SB][0] + (size_t)f_ * 16);                 \
        }                                                                   \
    }

    // prologue: stage tiles 0,1; tile 0 resident (tile 1's 6 loads in flight)
    STAGE_A(0, 0); STAGE_B(0, 0);
    STAGE_A(1, 1); STAGE_B(1, 1);
    asm volatile("s_waitcnt vmcnt(6)" ::: "memory");
    __builtin_amdgcn_s_barrier();

    int cb = 0;                          // buffer of tile tk
    for (int tk = 0; tk < NT; ++tk) {
        const u16* Ab = &A_s[cb][0];
        const u16* Bb = &B_s[cb][0];
        const int sb = (cb + 2 >= 3) ? cb - 1 : cb + 2;   // buffer of tile tk+2
        bf16x8 av[4], bv[4];

        // phase 1: C-rows [0,64)
#pragma unroll
        for (int j = 0; j < 4; ++j)
            bv[j] = *(const bf16x8*)(Bb + (w * 64 + j * 16 + lr) * 32 + hofs);
#pragma unroll
        for (int i = 0; i < 4; ++i)
            av[i] = *(const bf16x8*)(Ab + (i * 16 + lr) * 32 + hofs);
        if (tk + 2 < NT) STAGE_A(tk + 2, sb);
        __builtin_amdgcn_s_setprio(1);
#pragma unroll
        for (int i = 0; i < 4; ++i)
#pragma unroll
            for (int j = 0; j < 4; ++j)
                acc[i][j] = __builtin_amdgcn_mfma_f32_16x16x32_bf16(
                    av[i], bv[j], acc[i][j], 0, 0, 0);
        __builtin_amdgcn_s_setprio(0);

        // phase 2: C-rows [64,128), reuse bv
#pragma unroll
        for (int i = 0; i < 4; ++i)
            av[i] = *(const bf16x8*)(Ab + (64 + i * 16 + lr) * 32 + hofs);
        if (tk + 2 < NT) STAGE_B(tk + 2, sb);
        __builtin_amdgcn_s_setprio(1);
#pragma unroll
        for (int i = 0; i < 4; ++i)
#pragma unroll
            for (int j = 0; j < 4; ++j)
                acc[4 + i][j] = __builtin_amdgcn_mfma_f32_16x16x32_bf16(
                    av[i], bv[j], acc[4 + i][j], 0, 0, 0);
        __builtin_amdgcn_s_setprio(0);

        // tile tk+1 must be resident before next step; keep tk+2 in flight
        if (tk + 2 < NT)      asm volatile("s_waitcnt vmcnt(6)" ::: "memory");
        else if (tk + 1 < NT) asm volatile("s_waitcnt vmcnt(0)" ::: "memory");
        __builtin_amdgcn_s_barrier();
        cb = (cb + 1 >= 3) ? 0 : cb + 1;
    }
#undef STAGE_A
#undef STAGE_B

    const int r0c = (lane >> 4) << 2, cc = lane & 15;
#pragma unroll
    for (int mi = 0; mi < 8; ++mi)
#pragma unroll
        for (int j = 0; j < 4; ++j)
#pragma unroll
            for (int r = 0; r < 4; ++r) {
                size_t row = (size_t)(m0 + (mi >> 2) * 64 + (mi & 3) * 16 + r0c + r);
                size_t col = (size_t)(n0 + w * 64 + j * 16 + cc);
                size_t idx = row * (size_t)N + col;
                float v = acc[mi][j][r];
                if (EPI == 0) {
                    gh[idx] = f2bf(v);
                } else if (EPI == 1) {
                    float g  = bf2f(gh[idx]);
                    float sg = g / (1.0f + __expf(-g));
                    gh[idx] = f2bf(sg * v);
                } else {
                    outp[idx] = v;
                }
            }
}

// ---- 128-tile fallback GEMM (small-workspace path) ----
template <int AMODE, int EPI>
__global__ __launch_bounds__(256, 2) void gemm_k(
    const void* __restrict__ Ap, const u16* __restrict__ Bt,
    u16* __restrict__ ghp, float* __restrict__ outp, int M, int N, int K)
{
    __shared__ __align__(16) u16 A_s[128 * 32];
    __shared__ __align__(16) u16 B_s[128 * 32];

    const int nb = N >> 7;
    int mb, nbk; swz(blockIdx.x, nb, mb, nbk);
    const int m0 = mb << 7, n0 = nbk << 7;
    const int t = threadIdx.x, lane = t & 63, w = t >> 6;
    const int wy = w >> 1, wx = w & 1;
    const int lr = lane & 15, kq = (lane >> 4) << 3;

    f32x4 acc[4][4] = {};

    for (int kt = 0; kt < K; kt += 32) {
#pragma unroll
        for (int i = 0; i < 2; ++i) {
            int f   = (w * 2 + i) * 64 + lane;
            int row = f >> 2;
            int ko  = (f & 3) << 3;
            gl_lds16(Bt + (size_t)(n0 + row) * K + kt + ko,
                     (char*)B_s + ((w * 2 + i) << 10));
        }
        if (AMODE == 1) {
            const u16* ab = (const u16*)Ap;
#pragma unroll
            for (int i = 0; i < 2; ++i) {
                int f   = (w * 2 + i) * 64 + lane;
                int row = f >> 2;
                int ko  = (f & 3) << 3;
                gl_lds16(ab + (size_t)(m0 + row) * K + kt + ko,
                         (char*)A_s + ((w * 2 + i) << 10));
            }
        } else {
            const float* xa = (const float*)Ap;
#pragma unroll
            for (int i = 0; i < 4; ++i) {
                int c   = t + (i << 8);
                int row = c >> 3;
                int ko  = (c & 7) << 2;
                float4 v = *(const float4*)(xa + (size_t)(m0 + row) * K + kt + ko);
                u16x4 p;
                p[0] = f2bf(v.x); p[1] = f2bf(v.y); p[2] = f2bf(v.z); p[3] = f2bf(v.w);
                *(u16x4*)&A_s[row * 32 + ko] = p;
            }
        }
        __syncthreads();

        bf16x8 af[4], bv[4];
#pragma unroll
        for (int i = 0; i < 4; ++i)
            af[i] = *(const bf16x8*)&A_s[(wy * 64 + i * 16 + lr) * 32 + kq];
#pragma unroll
        for (int j = 0; j < 4; ++j)
            bv[j] = *(const bf16x8*)&B_s[(wx * 64 + j * 16 + lr) * 32 + kq];
#pragma unroll
        for (int i = 0; i < 4; ++i)
#pragma unroll
            for (int j = 0; j < 4; ++j)
                acc[i][j] = __builtin_amdgcn_mfma_f32_16x16x32_bf16(
                    af[i], bv[j], acc[i][j], 0, 0, 0);
        __syncthreads();
    }

    const int r0 = (lane >> 4) << 2, cc = lane & 15;
#pragma unroll
    for (int i = 0; i < 4; ++i)
#pragma unroll
        for (int j = 0; j < 4; ++j)
#pragma unroll
            for (int r = 0; r < 4; ++r) {
                size_t row = (size_t)(m0 + wy * 64 + i * 16 + r0 + r);
                size_t col = (size_t)(n0 + wx * 64 + j * 16 + cc);
                size_t idx = row * (size_t)N + col;
                float v = acc[i][j][r];
                if (EPI == 0) {
                    ghp[idx] = f2bf(v);
                } else if (EPI == 1) {
                    float g  = bf2f(ghp[idx]);
                    float sg = g / (1.0f + __expf(-g));
                    ghp[idx] = f2bf(sg * v);
                } else {
                    outp[idx] = v;
                }
            }
}

extern "C" void kernel_launch(void* const* d_in, const int* in_sizes, int n_in,
                              void* d_out, int out_size, void* d_ws, size_t ws_size,
                              hipStream_t stream) {
    const float* x  = (const float*)d_in[0];
    const int*   gq = (const int*)  d_in[1];
    const float* gs = (const float*)d_in[2];
    const float* gz = (const float*)d_in[3];
    const int*   uq = (const int*)  d_in[4];
    const float* us = (const float*)d_in[5];
    const float* uz = (const float*)d_in[6];
    const int*   dq = (const int*)  d_in[7];
    const float* dsc= (const float*)d_in[8];
    const float* dz = (const float*)d_in[9];
    float* out = (float*)d_out;

    const int D = 4096, I = 11008, M = 8192;
    const size_t xb_b = (size_t)M * D * 2;   //  67.1 MB
    const size_t w_b  = (size_t)I * D * 2;   //  90.2 MB
    const size_t gh_b = (size_t)M * I * 2;   // 180.4 MB

    dim3 blk(256);

    if (ws_size >= xb_b + 2 * w_b + gh_b) {
        // fast path: xb | Wg | Wu | gh ; Wd reuses Wg slot after gate gemm
        u16* xb = (u16*)d_ws;
        u16* Wg = (u16*)((char*)d_ws + xb_b);
        u16* Wu = (u16*)((char*)d_ws + xb_b + w_b);
        u16* gh = (u16*)((char*)d_ws + xb_b + 2 * w_b);
        u16* Wd = Wg;

        xcvt<<<(M * D) / (256 * 8), blk, 0, stream>>>(x, xb);
        dequant_t<<<dim3(I / 64, D / 128), blk, 0, stream>>>(gq, gs, gz, Wg, D, I);
        dequant_t<<<dim3(I / 64, D / 128), blk, 0, stream>>>(uq, us, uz, Wu, D, I);
        // gate: gh = x*Wg (bf16)
        gemmC<0><<<(M / 128) * (I / 256), blk, 0, stream>>>(xb, Wg, gh, nullptr, M, I, D);
        dequant_t<<<dim3(D / 64, I / 128), blk, 0, stream>>>(dq, dsc, dz, Wd, I, D);
        // up: gh = silu(gh) * (x*Wu), in place
        gemmC<1><<<(M / 128) * (I / 256), blk, 0, stream>>>(xb, Wu, gh, nullptr, M, I, D);
        // down: out = gh * Wd (fp32)
        gemmC<2><<<(M / 128) * (D / 256), blk, 0, stream>>>(gh, Wd, nullptr, out, M, D, I);
    } else {
        // fallback: sequential R1 layout (Wt | gh)
        u16* Wt = (u16*)d_ws;
        u16* gh = (u16*)((char*)d_ws + w_b);

        dequant_t<<<dim3(I / 64, D / 128), blk, 0, stream>>>(gq, gs, gz, Wt, D, I);
        gemm_k<0, 0><<<(M / 128) * (I / 128), blk, 0, stream>>>(x, Wt, gh, nullptr, M, I, D);
        dequant_t<<<dim3(I / 64, D / 128), blk, 0, stream>>>(uq, us, uz, Wt, D, I);
        gemm_k<0, 1><<<(M / 128) * (I / 128), blk, 0, stream>>>(x, Wt, gh, nullptr, M, I, D);
        dequant_t<<<dim3(D / 64, I / 128), blk, 0, stream>>>(dq, dsc, dz, Wt, I, D);
        gemm_k<1, 2><<<(M / 128) * (D / 128), blk, 0, stream>>>(gh, Wt, nullptr, out, M, D, I);
    }
}

// Round 4
// 2901.735 us; speedup vs baseline: 1.1966x; 1.1966x over previous
//
#include <hip/hip_runtime.h>

typedef unsigned short u16;
typedef __bf16 bf16x8 __attribute__((ext_vector_type(8)));
typedef float f32x4 __attribute__((ext_vector_type(4)));
typedef unsigned short u16x4 __attribute__((ext_vector_type(4)));
typedef unsigned short u16x8 __attribute__((ext_vector_type(8)));

__device__ __forceinline__ u16 f2bf(float f) {
    union { float f; unsigned u; } v; v.f = f;
    unsigned r = v.u + 0x7FFFu + ((v.u >> 16) & 1u);   // RTNE
    return (u16)(r >> 16);
}
__device__ __forceinline__ float bf2f(u16 h) {
    union { unsigned u; float f; } v; v.u = ((unsigned)h) << 16;
    return v.f;
}

// async global->LDS, 16B per lane; LDS dest is wave-uniform base + lane*16
__device__ __forceinline__ void gl_lds16(const void* gp, void* lp) {
    __builtin_amdgcn_global_load_lds(
        reinterpret_cast<__attribute__((address_space(1))) unsigned int*>(
            reinterpret_cast<size_t>(gp)),
        reinterpret_cast<__attribute__((address_space(3))) unsigned int*>(
            reinterpret_cast<size_t>(lp)),
        16, 0, 0);
}

// compiler memory fence + hw barrier (pins phase rhythm; no codegen cost for fence)
#define BAR() { asm volatile("" ::: "memory"); __builtin_amdgcn_s_barrier(); asm volatile("" ::: "memory"); }

// GROUP_M=8 swizzle for the 128-tile fallback kernel
__device__ __forceinline__ void swz(int bid, int nb, int& mb, int& nbk) {
    int gs  = nb << 3;
    int grp = bid / gs;
    int rem = bid - grp * gs;
    mb  = (grp << 3) + (rem & 7);
    nbk = rem >> 3;
}

// ---- x fp32 -> bf16, 8 elems/thread, exact grid ----
__global__ __launch_bounds__(256) void xcvt(const float* __restrict__ x,
                                            u16* __restrict__ xb) {
    size_t i = ((size_t)blockIdx.x * 256 + threadIdx.x) * 8;
    float4 a = *(const float4*)(x + i);
    float4 b = *(const float4*)(x + i + 4);
    u16x8 p;
    p[0] = f2bf(a.x); p[1] = f2bf(a.y); p[2] = f2bf(a.z); p[3] = f2bf(a.w);
    p[4] = f2bf(b.x); p[5] = f2bf(b.y); p[6] = f2bf(b.z); p[7] = f2bf(b.w);
    *(u16x8*)(xb + i) = p;
}

// ---- transpose-dequant via LDS: q[K,N] int32 -> wt[N,K] bf16 ----
__global__ __launch_bounds__(256) void dequant_t(
    const int* __restrict__ q, const float* __restrict__ s,
    const float* __restrict__ z, u16* __restrict__ wt, int K, int N)
{
    __shared__ u16 ls[64 * 132];
    const int n0 = blockIdx.x * 64, k0 = blockIdx.y * 128;
    const int g  = k0 >> 7;
    const int t  = threadIdx.x;
    const int n4 = (t & 15) * 4;
    const int kb = t >> 4;
    float sv[4], zv[4];
#pragma unroll
    for (int j = 0; j < 4; ++j) {
        sv[j] = s[(size_t)g * N + n0 + n4 + j];
        zv[j] = z[(size_t)g * N + n0 + n4 + j];
    }
#pragma unroll
    for (int p = 0; p < 8; ++p) {
        int kk = kb + p * 16;
        int4 qv = *(const int4*)(q + (size_t)(k0 + kk) * N + n0 + n4);
        ls[(n4 + 0) * 132 + kk] = f2bf((float)(qv.x - 8) * sv[0] + zv[0]);
        ls[(n4 + 1) * 132 + kk] = f2bf((float)(qv.y - 8) * sv[1] + zv[1]);
        ls[(n4 + 2) * 132 + kk] = f2bf((float)(qv.z - 8) * sv[2] + zv[2]);
        ls[(n4 + 3) * 132 + kk] = f2bf((float)(qv.w - 8) * sv[3] + zv[3]);
    }
    __syncthreads();
    const int r = t >> 2, c = t & 3;
    const u16* src = &ls[r * 132 + c * 32];
    u16* dst = &wt[(size_t)(n0 + r) * K + k0 + c * 32];
#pragma unroll
    for (int i = 0; i < 4; ++i) {
        u16x4 a = *(const u16x4*)(src + i * 8);
        u16x4 b = *(const u16x4*)(src + i * 8 + 4);
        u16x8 v;
        v[0] = a[0]; v[1] = a[1]; v[2] = a[2]; v[3] = a[3];
        v[4] = b[0]; v[5] = b[1]; v[6] = b[2]; v[7] = b[3];
        *(u16x8*)(dst + i * 8) = v;
    }
}

// ---- 256x256-tile 8-phase GEMM (m201-style): C[m,n] = sum_k A[m,k]*Bt[n,k]
// 512 threads = 8 waves (2M x 4N), BK=64, per-wave C = 128x64.
// LDS: 2 dbuf x {A,B} x 2 halves x [128 rows][64 k] = 128 KiB.
//   A-half h = m-rows with (row&64)==h*64;  B-half h = n-rows with (row&32)==h*32
//   -> every phase's ds_reads hit exactly one half, uniformly across waves.
// Per K-tile: 4 phases = C-quadrants (A0B0)(A0B1)(A1B1)(A1B0), 16 MFMA each.
// Each phase stages ONE half-tile (2 x global_load_lds dwordx4) of a future
// tile into the slot freed >=1 phase earlier:
//   P1:B0(t+1) P2:A1(t+1) P3:A0(t+2) P4:B1(t+2) P5:B0(t+2) P6:A1(t+2)
//   P7:A0(t+3) P8:B1(t+3)
// Counted s_waitcnt vmcnt(4) at P4/P8 only (2 half-tiles stay in flight;
// never drains to 0 until the final iteration).
// Swizzle: LDS chunk slot s, global chunk c = (s&4)|((s&3)^((row>>1)&3))
// (inverse-swizzled source + swizzled read; 0 bank conflicts, rounds 1-3).
// EPI: 0 = store bf16 to gh; 1 = gh = silu(gh)*acc (in place); 2 = fp32 out.
template <int EPI>
__global__ __launch_bounds__(512, 2) void gemm8p(
    const u16* __restrict__ A, const u16* __restrict__ Bt,
    u16* __restrict__ gh, float* __restrict__ outp, int M, int N, int K)
{
    __shared__ __align__(16) u16 As[2][2][128 * 64];   // [dbuf][half]
    __shared__ __align__(16) u16 Bs[2][2][128 * 64];

    const int nb  = N >> 8;
    const int bid = blockIdx.x, nwg = gridDim.x;   // nwg % 8 == 0 by launch
    const int cpx = nwg >> 3;                      // XCD-bijective swizzle
    const int wg  = (bid & 7) * cpx + (bid >> 3);
    const int mb  = wg / nb, nbk = wg - mb * nb;
    const int m0 = mb << 8, n0 = nbk << 8;

    const int t = threadIdx.x, lane = t & 63, w = t >> 6;
    const int wm = w >> 2, wn = w & 3;
    const int lr = lane & 15;
    const int qofs = (((lane >> 4) ^ ((lr >> 1) & 3)) << 3);   // swizzled chunk, elems

    f32x4 acc[8][4] = {};
    bf16x8 av[4][2], bv[2][2];

    const int NT = K >> 6;        // 64-wide K-tiles (K=4096->64, K=11008->172)
    const int NI = NT >> 1;       // 8-phase iterations (2 tiles each)

#define STG_A(TT, DB, H)                                                    \
    {                                                                       \
        const int ko_ = (TT) << 6;                                          \
        _Pragma("unroll")                                                   \
        for (int l_ = 0; l_ < 2; ++l_) {                                    \
            int f_  = l_ * 512 + t;                                         \
            int r_  = f_ >> 3, s_ = f_ & 7;                                 \
            int c_  = (s_ & 4) | ((s_ & 3) ^ ((r_ >> 1) & 3));              \
            int gr_ = ((r_ >> 6) << 7) + ((H) << 6) + (r_ & 63);            \
            gl_lds16(A + (size_t)(m0 + gr_) * K + ko_ + c_ * 8,             \
                     (char*)&As[DB][H][0] + f_ * 16);                       \
        }                                                                   \
    }
#define STG_B(TT, DB, H)                                                    \
    {                                                                       \
        const int ko_ = (TT) << 6;                                          \
        _Pragma("unroll")                                                   \
        for (int l_ = 0; l_ < 2; ++l_) {                                    \
            int f_  = l_ * 512 + t;                                         \
            int r_  = f_ >> 3, s_ = f_ & 7;                                 \
            int c_  = (s_ & 4) | ((s_ & 3) ^ ((r_ >> 1) & 3));              \
            int gr_ = ((r_ >> 5) << 6) + ((H) << 5) + (r_ & 31);            \
            gl_lds16(Bt + (size_t)(n0 + gr_) * K + ko_ + c_ * 8,            \
                     (char*)&Bs[DB][H][0] + f_ * 16);                       \
        }                                                                   \
    }
#define LDA(DB, H)                                                          \
    _Pragma("unroll")                                                       \
    for (int fa_ = 0; fa_ < 4; ++fa_)                                       \
        _Pragma("unroll")                                                   \
        for (int kk_ = 0; kk_ < 2; ++kk_)                                   \
            av[fa_][kk_] = *(const bf16x8*)&As[DB][H][                      \
                (wm * 64 + fa_ * 16 + lr) * 64 + kk_ * 32 + qofs];
#define LDB(DB, H)                                                          \
    _Pragma("unroll")                                                       \
    for (int bb_ = 0; bb_ < 2; ++bb_)                                       \
        _Pragma("unroll")                                                   \
        for (int kk_ = 0; kk_ < 2; ++kk_)                                   \
            bv[bb_][kk_] = *(const bf16x8*)&Bs[DB][H][                      \
                (wn * 32 + bb_ * 16 + lr) * 64 + kk_ * 32 + qofs];
#define MM(AB, BB)                                                          \
    __builtin_amdgcn_s_setprio(1);                                          \
    _Pragma("unroll")                                                       \
    for (int fa_ = 0; fa_ < 4; ++fa_)                                       \
        _Pragma("unroll")                                                   \
        for (int bb_ = 0; bb_ < 2; ++bb_)                                   \
            _Pragma("unroll")                                               \
            for (int kk_ = 0; kk_ < 2; ++kk_)                               \
                acc[(AB) + fa_][(BB) + bb_] =                               \
                    __builtin_amdgcn_mfma_f32_16x16x32_bf16(                \
                        av[fa_][kk_], bv[bb_][kk_],                         \
                        acc[(AB) + fa_][(BB) + bb_], 0, 0, 0);              \
    __builtin_amdgcn_s_setprio(0);

    // prologue: tile0 complete (oldest), then A0(1), B1(1) (2 halves in flight)
    STG_A(0, 0, 0); STG_B(0, 0, 0); STG_A(0, 0, 1); STG_B(0, 0, 1);
    STG_A(1, 1, 0); STG_B(1, 1, 1);
    asm volatile("s_waitcnt vmcnt(4)" ::: "memory");
    BAR();

    for (int it = 0; it < NI; ++it) {
        const int T = it << 1;
        const bool more = (it < NI - 1);

        // ---- tile T (dbuf 0) ----
        LDA(0, 0); LDB(0, 0);              // P1: quadrant (A0,B0)
        STG_B(T + 1, 1, 0);
        BAR(); MM(0, 0); BAR();

        LDB(0, 1);                          // P2: (A0,B1)
        STG_A(T + 1, 1, 1);
        BAR(); MM(0, 2); BAR();

        LDA(0, 1);                          // P3: (A1,B1)
        if (more) STG_A(T + 2, 0, 0);
        BAR(); MM(4, 2); BAR();

        LDB(0, 0);                          // P4: (A1,B0)
        if (more) STG_B(T + 2, 0, 1);
        BAR(); MM(4, 0);
        if (more) { asm volatile("s_waitcnt vmcnt(4)" ::: "memory"); }
        else      { asm volatile("s_waitcnt vmcnt(0)" ::: "memory"); }
        BAR();

        // ---- tile T+1 (dbuf 1) ----
        LDA(1, 0); LDB(1, 0);              // P5: (A0,B0)
        if (more) STG_B(T + 2, 0, 0);
        BAR(); MM(0, 0); BAR();

        LDB(1, 1);                          // P6: (A0,B1)
        if (more) STG_A(T + 2, 0, 1);
        BAR(); MM(0, 2); BAR();

        LDA(1, 1);                          // P7: (A1,B1)
        if (more) STG_A(T + 3, 1, 0);
        BAR(); MM(4, 2); BAR();

        LDB(1, 0);                          // P8: (A1,B0)
        if (more) STG_B(T + 3, 1, 1);
        BAR(); MM(4, 0);
        if (more) { asm volatile("s_waitcnt vmcnt(4)" ::: "memory"); }
        BAR();
    }
#undef STG_A
#undef STG_B
#undef LDA
#undef LDB
#undef MM

    const int r0c = (lane >> 4) << 2, cc = lane & 15;
#pragma unroll
    for (int a = 0; a < 8; ++a)
#pragma unroll
        for (int b = 0; b < 4; ++b)
#pragma unroll
            for (int r = 0; r < 4; ++r) {
                size_t row = (size_t)(m0 + wm * 128 + a * 16 + r0c + r);
                size_t col = (size_t)(n0 + wn * 64 + b * 16 + cc);
                size_t idx = row * (size_t)N + col;
                float v = acc[a][b][r];
                if (EPI == 0) {
                    gh[idx] = f2bf(v);
                } else if (EPI == 1) {
                    float g  = bf2f(gh[idx]);
                    float sg = g / (1.0f + __expf(-g));
                    gh[idx] = f2bf(sg * v);
                } else {
                    outp[idx] = v;
                }
            }
}

// ---- 128-tile fallback GEMM (small-workspace path) ----
template <int AMODE, int EPI>
__global__ __launch_bounds__(256, 2) void gemm_k(
    const void* __restrict__ Ap, const u16* __restrict__ Bt,
    u16* __restrict__ ghp, float* __restrict__ outp, int M, int N, int K)
{
    __shared__ __align__(16) u16 A_s[128 * 32];
    __shared__ __align__(16) u16 B_s[128 * 32];

    const int nb = N >> 7;
    int mb, nbk; swz(blockIdx.x, nb, mb, nbk);
    const int m0 = mb << 7, n0 = nbk << 7;
    const int t = threadIdx.x, lane = t & 63, w = t >> 6;
    const int wy = w >> 1, wx = w & 1;
    const int lr = lane & 15, kq = (lane >> 4) << 3;

    f32x4 acc[4][4] = {};

    for (int kt = 0; kt < K; kt += 32) {
#pragma unroll
        for (int i = 0; i < 2; ++i) {
            int f   = (w * 2 + i) * 64 + lane;
            int row = f >> 2;
            int ko  = (f & 3) << 3;
            gl_lds16(Bt + (size_t)(n0 + row) * K + kt + ko,
                     (char*)B_s + ((w * 2 + i) << 10));
        }
        if (AMODE == 1) {
            const u16* ab = (const u16*)Ap;
#pragma unroll
            for (int i = 0; i < 2; ++i) {
                int f   = (w * 2 + i) * 64 + lane;
                int row = f >> 2;
                int ko  = (f & 3) << 3;
                gl_lds16(ab + (size_t)(m0 + row) * K + kt + ko,
                         (char*)A_s + ((w * 2 + i) << 10));
            }
        } else {
            const float* xa = (const float*)Ap;
#pragma unroll
            for (int i = 0; i < 4; ++i) {
                int c   = t + (i << 8);
                int row = c >> 3;
                int ko  = (c & 7) << 2;
                float4 v = *(const float4*)(xa + (size_t)(m0 + row) * K + kt + ko);
                u16x4 p;
                p[0] = f2bf(v.x); p[1] = f2bf(v.y); p[2] = f2bf(v.z); p[3] = f2bf(v.w);
                *(u16x4*)&A_s[row * 32 + ko] = p;
            }
        }
        __syncthreads();

        bf16x8 af[4], bv[4];
#pragma unroll
        for (int i = 0; i < 4; ++i)
            af[i] = *(const bf16x8*)&A_s[(wy * 64 + i * 16 + lr) * 32 + kq];
#pragma unroll
        for (int j = 0; j < 4; ++j)
            bv[j] = *(const bf16x8*)&B_s[(wx * 64 + j * 16 + lr) * 32 + kq];
#pragma unroll
        for (int i = 0; i < 4; ++i)
#pragma unroll
            for (int j = 0; j < 4; ++j)
                acc[i][j] = __builtin_amdgcn_mfma_f32_16x16x32_bf16(
                    af[i], bv[j], acc[i][j], 0, 0, 0);
        __syncthreads();
    }

    const int r0 = (lane >> 4) << 2, cc = lane & 15;
#pragma unroll
    for (int i = 0; i < 4; ++i)
#pragma unroll
        for (int j = 0; j < 4; ++j)
#pragma unroll
            for (int r = 0; r < 4; ++r) {
                size_t row = (size_t)(m0 + wy * 64 + i * 16 + r0 + r);
                size_t col = (size_t)(n0 + wx * 64 + j * 16 + cc);
                size_t idx = row * (size_t)N + col;
                float v = acc[i][j][r];
                if (EPI == 0) {
                    ghp[idx] = f2bf(v);
                } else if (EPI == 1) {
                    float g  = bf2f(ghp[idx]);
                    float sg = g / (1.0f + __expf(-g));
                    ghp[idx] = f2bf(sg * v);
                } else {
                    outp[idx] = v;
                }
            }
}

extern "C" void kernel_launch(void* const* d_in, const int* in_sizes, int n_in,
                              void* d_out, int out_size, void* d_ws, size_t ws_size,
                              hipStream_t stream) {
    const float* x  = (const float*)d_in[0];
    const int*   gq = (const int*)  d_in[1];
    const float* gs = (const float*)d_in[2];
    const float* gz = (const float*)d_in[3];
    const int*   uq = (const int*)  d_in[4];
    const float* us = (const float*)d_in[5];
    const float* uz = (const float*)d_in[6];
    const int*   dq = (const int*)  d_in[7];
    const float* dsc= (const float*)d_in[8];
    const float* dz = (const float*)d_in[9];
    float* out = (float*)d_out;

    const int D = 4096, I = 11008, M = 8192;
    const size_t xb_b = (size_t)M * D * 2;   //  67.1 MB
    const size_t w_b  = (size_t)I * D * 2;   //  90.2 MB
    const size_t gh_b = (size_t)M * I * 2;   // 180.4 MB

    dim3 blk(256);
    dim3 blk5(512);

    if (ws_size >= xb_b + 2 * w_b + gh_b) {
        // fast path: xb | Wg | Wu | gh ; Wd reuses Wg slot after gate gemm
        u16* xb = (u16*)d_ws;
        u16* Wg = (u16*)((char*)d_ws + xb_b);
        u16* Wu = (u16*)((char*)d_ws + xb_b + w_b);
        u16* gh = (u16*)((char*)d_ws + xb_b + 2 * w_b);
        u16* Wd = Wg;

        xcvt<<<(M * D) / (256 * 8), blk, 0, stream>>>(x, xb);
        dequant_t<<<dim3(I / 64, D / 128), blk, 0, stream>>>(gq, gs, gz, Wg, D, I);
        dequant_t<<<dim3(I / 64, D / 128), blk, 0, stream>>>(uq, us, uz, Wu, D, I);
        // gate: gh = x*Wg (bf16)
        gemm8p<0><<<(M / 256) * (I / 256), blk5, 0, stream>>>(xb, Wg, gh, nullptr, M, I, D);
        dequant_t<<<dim3(D / 64, I / 128), blk, 0, stream>>>(dq, dsc, dz, Wd, I, D);
        // up: gh = silu(gh) * (x*Wu), in place
        gemm8p<1><<<(M / 256) * (I / 256), blk5, 0, stream>>>(xb, Wu, gh, nullptr, M, I, D);
        // down: out = gh * Wd (fp32)
        gemm8p<2><<<(M / 256) * (D / 256), blk5, 0, stream>>>(gh, Wd, nullptr, out, M, D, I);
    } else {
        // fallback: sequential R1 layout (Wt | gh)
        u16* Wt = (u16*)d_ws;
        u16* gh = (u16*)((char*)d_ws + w_b);

        dequant_t<<<dim3(I / 64, D / 128), blk, 0, stream>>>(gq, gs, gz, Wt, D, I);
        gemm_k<0, 0><<<(M / 128) * (I / 128), blk, 0, stream>>>(x, Wt, gh, nullptr, M, I, D);
        dequant_t<<<dim3(I / 64, D / 128), blk, 0, stream>>>(uq, us, uz, Wt, D, I);
        gemm_k<0, 1><<<(M / 128) * (I / 128), blk, 0, stream>>>(x, Wt, gh, nullptr, M, I, D);
        dequant_t<<<dim3(D / 64, I / 128), blk, 0, stream>>>(dq, dsc, dz, Wt, I, D);
        gemm_k<1, 2><<<(M / 128) * (D / 128), blk, 0, stream>>>(gh, Wt, nullptr, out, M, D, I);
    }
}